// Round 3
// baseline (259.129 us; speedup 1.0000x reference)
//
#include <hip/hip_runtime.h>
#include <cmath>

#define B_ 4
#define L_ 2048
#define S_ 2048
#define H_ 16
#define E_ 64
// 1/sqrt(64) * log2(e): exp2 (single v_exp_f32) instead of exp
#define SCALE2 0.18033688011112042f

typedef __attribute__((ext_vector_type(4))) float f32x4;
typedef __attribute__((ext_vector_type(8))) __bf16 bf16x8;
typedef __attribute__((ext_vector_type(8))) unsigned short ushort8;
union FragU { ushort8 u; bf16x8 b; unsigned int d[4]; };

__device__ __forceinline__ unsigned short f2bf(float f) {
    unsigned int u = __float_as_uint(f);
    return (unsigned short)((u + 0x7FFFu + ((u >> 16) & 1u)) >> 16);
}

// pack two fp32 (truncate) into one dword of 2 bf16: {hi[31:16], lo[31:16]}
__device__ __forceinline__ unsigned int pack_bf(float hi, float lo) {
    return __builtin_amdgcn_perm(__float_as_uint(hi), __float_as_uint(lo),
                                 0x07060302u);
}

__device__ __forceinline__ void gload_lds16(const void* g, void* l) {
    __builtin_amdgcn_global_load_lds(
        (const __attribute__((address_space(1))) void*)g,
        (__attribute__((address_space(3))) void*)l, 16, 0, 0);
}

// ---- Prepass: K [b,s,h,e] fp32 -> Kbf [b,h,s,e] bf16, 16B chunks XOR-swizzled
// within each key row (dst chunk j holds src chunk j^(s&7)).
__global__ __launch_bounds__(256) void conv_k(const float* __restrict__ K,
                                              unsigned short* __restrict__ Kbf) {
    const int idx = blockIdx.x * 256 + threadIdx.x;
    const int j   = idx & 7;
    const int row = idx >> 3;            // (b*H+h)*S + s
    const int s   = row & (S_ - 1);
    const int bh  = row >> 11;
    const int h   = bh & (H_ - 1);
    const int b   = bh >> 4;
    const int jp  = j ^ (s & 7);
    const float* src = K + (((size_t)b * S_ + s) * H_ + h) * E_ + jp * 8;
    f32x4 a = *(const f32x4*)src;
    f32x4 d = *(const f32x4*)(src + 4);
    ushort8 u;
    u[0]=f2bf(a[0]); u[1]=f2bf(a[1]); u[2]=f2bf(a[2]); u[3]=f2bf(a[3]);
    u[4]=f2bf(d[0]); u[5]=f2bf(d[1]); u[6]=f2bf(d[2]); u[7]=f2bf(d[3]);
    *(ushort8*)(Kbf + (size_t)row * E_ + j * 8) = u;
}

// ---- Prepass: V [b,s,h,e] fp32 -> Vt [b,h,e,s'] bf16, transposed per head,
// with the PERMUTED-K interleave baked in: within each 64-key block, stored
// chunk cc (= q*2+half) holds keys {(2*half+d)*16 + q*4 + r : d=0,1; r=0..3},
// then chunks XOR-swizzled by (e&7). This makes the main kernel's V B-frags
// (k = quad*8+j <-> key = (j>=4?n_hi:n_lo)*16+quad*4+(j&3)) plain b128 reads.
__global__ __launch_bounds__(256) void conv_v(const float* __restrict__ V,
                                              unsigned short* __restrict__ Vt) {
    __shared__ unsigned short t[64 * 65];
    const int tid  = threadIdx.x;
    const int sblk = blockIdx.x & 31;
    const int h    = (blockIdx.x >> 5) & 15;
    const int b    = blockIdx.x >> 9;
    const int s0   = sblk * 64;
    for (int i = 0; i < 4; ++i) {
        const int c = tid + i * 256;
        const int sr = c >> 4, e0 = (c & 15) * 4;
        f32x4 a = *(const f32x4*)(V + (((size_t)b * S_ + s0 + sr) * H_ + h) * E_ + e0);
        t[sr * 65 + e0 + 0] = f2bf(a[0]);
        t[sr * 65 + e0 + 1] = f2bf(a[1]);
        t[sr * 65 + e0 + 2] = f2bf(a[2]);
        t[sr * 65 + e0 + 3] = f2bf(a[3]);
    }
    __syncthreads();
    for (int i = 0; i < 2; ++i) {
        const int c  = tid + i * 256;
        const int e  = c >> 3, cc = c & 7;
        const int q  = cc >> 1, half = cc & 1;
        ushort8 u;
        for (int j = 0; j < 8; ++j) {
            const int d = j >> 2, r = j & 3;
            const int key = (2 * half + d) * 16 + q * 4 + r;
            u[j] = t[key * 65 + e];
        }
        *(ushort8*)(Vt + ((size_t)(b * H_ + h) * E_ + e) * S_ + s0
                    + (cc ^ (e & 7)) * 8) = u;
    }
}

// ---- Main: 4 waves x 32 q-rows = 128 q-rows/block, two 16-row groups per
// wave sharing every K/V LDS fragment. R3: staging-latency fix.
//   (a) depth-2 prefetch: 3 LDS buffers, raw s_barrier + counted
//       s_waitcnt vmcnt(4) -- tile kt+1's global_load_lds stays in flight
//       ACROSS the barrier (T4); only the 2-iteration-old stage is awaited.
//   (b) XCD co-location: h = blockIdx.x so all 16 q-tiles of a (b,h) share
//       dispatch id%8 (same XCD); per-XCD K/V working set = 4MB = its L2.
//   (c) row-sum l via ones-column MFMA into lacc (idle MFMA pipe) instead
//       of 32 VALU adds/tile; epilogue reads lacc[g][r] directly, no shfl.
template <bool PRE>
__global__ __launch_bounds__(256, 4) void fattn_kernel(
    const float* __restrict__ Q, const unsigned short* __restrict__ Kbf,
    const unsigned short* __restrict__ Vt, const float* __restrict__ Kf,
    const float* __restrict__ Vf, float* __restrict__ Out)
{
    const int tid  = threadIdx.x;
    const int wave = tid >> 6;
    const int lane = tid & 63;
    const int ln   = lane & 15;
    const int quad = lane >> 4;
    const int h = blockIdx.x;            // id%8 == h%8 -> per-(b,h) XCD pin
    const int b = blockIdx.z;
    // qtile bijective in y per (h,b); co-resident blocks (ids +256k) differ
    // in z -> qtile spread by 4 -> per-CU work within ~18% of mean.
    const int qtile = (blockIdx.y + blockIdx.x + 4 * blockIdx.z) & 15;
    const int q0 = qtile * 128;
    const int qw = q0 + wave * 32;       // this wave's 32 q-rows
    const int p7 = ln & 7;

    __shared__ __align__(16) unsigned short ldsK[3][64 * 64];  // [key][e] swz
    __shared__ __align__(16) unsigned short ldsV[3][64 * 64];  // [e][key'] swz

    // Q fragments (B-operand for S^T; n=ln, k=c*32+quad*8+j), pre-scaled.
    FragU qf[2][2];
    #pragma unroll
    for (int g = 0; g < 2; ++g) {
        const float* qp = Q + (((size_t)b * L_ + (qw + g * 16 + ln)) * H_ + h) * E_;
        #pragma unroll
        for (int c = 0; c < 2; ++c) {
            const int e0 = c * 32 + quad * 8;
            f32x4 lo = *(const f32x4*)(qp + e0);
            f32x4 hi = *(const f32x4*)(qp + e0 + 4);
            ushort8 u;
            u[0]=f2bf(lo[0]*SCALE2); u[1]=f2bf(lo[1]*SCALE2);
            u[2]=f2bf(lo[2]*SCALE2); u[3]=f2bf(lo[3]*SCALE2);
            u[4]=f2bf(hi[0]*SCALE2); u[5]=f2bf(hi[1]*SCALE2);
            u[6]=f2bf(hi[2]*SCALE2); u[7]=f2bf(hi[3]*SCALE2);
            qf[g][c].u = u;
        }
    }

    FragU onef;                          // all-ones bf16 B-frag for l = P.1
    #pragma unroll
    for (int j = 0; j < 8; ++j) onef.u[j] = 0x3F80;

    f32x4 o[2][4];
    #pragma unroll
    for (int g = 0; g < 2; ++g)
        #pragma unroll
        for (int et = 0; et < 4; ++et) o[g][et] = f32x4{0.f, 0.f, 0.f, 0.f};
    f32x4 lacc[2];
    lacc[0] = f32x4{0.f, 0.f, 0.f, 0.f};
    lacc[1] = f32x4{0.f, 0.f, 0.f, 0.f};

    const unsigned short* kbh = Kbf + (size_t)(b * H_ + h) * S_ * E_;
    const unsigned short* vbh = Vt  + (size_t)(b * H_ + h) * E_ * S_;
    const float* kf32 = Kf + (((size_t)b * S_) * H_ + h) * E_;
    const float* vf32 = Vf + (((size_t)b * S_) * H_ + h) * E_;

    auto STAGE = [&](int bsel, int kt2) {
        const int k0s = kt2 * 64;
        if constexpr (PRE) {
            const unsigned short* ktb = kbh + (size_t)k0s * E_;
            const unsigned short* vtb = vbh + k0s;
            #pragma unroll
            for (int i = 0; i < 2; ++i) {          // K tile: 8KB linear DMA
                const int slot0 = wave * 128 + i * 64;
                gload_lds16(ktb + (size_t)(slot0 + lane) * 8,
                            &ldsK[bsel][slot0 * 8]);
            }
            #pragma unroll
            for (int i = 0; i < 2; ++i) {          // V tile: 64 rows x 128B DMA
                const int slot0 = wave * 128 + i * 64;
                const int slot  = slot0 + lane;
                const int e = slot >> 3, lc = slot & 7;
                gload_lds16(vtb + (size_t)e * S_ + lc * 8,
                            &ldsV[bsel][slot0 * 8]);
            }
        } else {
            #pragma unroll
            for (int i = 0; i < 2; ++i) {          // fp32 fallback staging
                const int c = tid + i * 256;
                const int key = c >> 3, j = c & 7, jp = j ^ (key & 7);
                const float* src = kf32 + (size_t)(k0s + key) * (H_ * E_) + jp * 8;
                f32x4 a = *(const f32x4*)src, d = *(const f32x4*)(src + 4);
                ushort8 u;
                u[0]=f2bf(a[0]); u[1]=f2bf(a[1]); u[2]=f2bf(a[2]); u[3]=f2bf(a[3]);
                u[4]=f2bf(d[0]); u[5]=f2bf(d[1]); u[6]=f2bf(d[2]); u[7]=f2bf(d[3]);
                *(ushort8*)&ldsK[bsel][key * 64 + j * 8] = u;
            }
            #pragma unroll
            for (int i = 0; i < 2; ++i) {          // V with permuted-k layout
                const int c = tid + i * 256;
                const int e = c >> 3, cc = c & 7;
                const int q = cc >> 1, half = cc & 1;
                ushort8 u;
                #pragma unroll
                for (int j = 0; j < 8; ++j) {
                    const int d = j >> 2, r = j & 3;
                    const int key = (2 * half + d) * 16 + q * 4 + r;
                    u[j] = f2bf(vf32[(size_t)(k0s + key) * (H_ * E_) + e]);
                }
                *(ushort8*)&ldsV[bsel][e * 64 + (cc ^ (e & 7)) * 8] = u;
            }
        }
    };

    const int ntiles = 2 * qtile + 2;    // keys 0 .. q0+127  (ntiles >= 2)
    STAGE(0, 0);
    STAGE(1, 1);
    int cur = 0;
    for (int kt = 0; kt < ntiles; ++kt) {
        // vmcnt retires IN ORDER: <=4 outstanding means stage(kt) landed
        // while stage(kt+1)'s 4 loads stay in flight across the barrier.
        if (kt + 1 < ntiles)
            asm volatile("s_waitcnt vmcnt(4) lgkmcnt(0)" ::: "memory");
        else
            asm volatile("s_waitcnt vmcnt(0) lgkmcnt(0)" ::: "memory");
        __builtin_amdgcn_s_barrier();
        __builtin_amdgcn_sched_barrier(0);   // pin ds_reads below the barrier
        if (kt + 2 < ntiles) {
            int sb = cur + 2; if (sb >= 3) sb -= 3;   // (kt+2)%3
            STAGE(sb, kt + 2);               // overwrites tile kt-1's buffer
        }

        const int k0 = kt * 64;
        if (k0 <= qw + 31) {             // wave-uniform skip of masked tiles
            __builtin_amdgcn_s_setprio(1);
            const unsigned short* bK = ldsK[cur];
            const unsigned short* bV = ldsV[cur];
            // Mask needed iff tile max key (k0+63) exceeds group's MIN row.
            const bool m0 = (k0 + 63 > qw);
            const bool m1 = (k0 + 63 > qw + 16);

            // S^T = K.Q^T : A = K-frag (m=key), B = Q-frag (n=qrow).
            FragU pf[2][2];
            #pragma unroll
            for (int n = 0; n < 4; ++n) {
                FragU kf0, kf1;
                kf0.u = *(const ushort8*)&bK[(n*16+ln)*64 + ((quad    ) ^ p7) * 8];
                kf1.u = *(const ushort8*)&bK[(n*16+ln)*64 + ((4 + quad) ^ p7) * 8];
                #pragma unroll
                for (int g = 0; g < 2; ++g) {
                    f32x4 acc = f32x4{0.f, 0.f, 0.f, 0.f};
                    acc = __builtin_amdgcn_mfma_f32_16x16x32_bf16(kf0.b, qf[g][0].b, acc, 0, 0, 0);
                    acc = __builtin_amdgcn_mfma_f32_16x16x32_bf16(kf1.b, qf[g][1].b, acc, 0, 0, 0);
                    const bool nm = g ? m1 : m0;
                    const int qrow = qw + g * 16 + ln;
                    float p[4];
                    #pragma unroll
                    for (int r = 0; r < 4; ++r) {
                        float v = __builtin_exp2f(acc[r]);
                        if (nm) {
                            const int key = k0 + n * 16 + quad * 4 + r;
                            v = (key <= qrow) ? v : 0.f;
                        }
                        p[r] = v;
                    }
                    pf[g][n >> 1].d[(n & 1) * 2 + 0] = pack_bf(p[1], p[0]);
                    pf[g][n >> 1].d[(n & 1) * 2 + 1] = pack_bf(p[3], p[2]);
                }
            }

            // l += P.1 on the (mostly idle) MFMA pipe; O += P.V.
            #pragma unroll
            for (int g = 0; g < 2; ++g) {
                lacc[g] = __builtin_amdgcn_mfma_f32_16x16x32_bf16(pf[g][0].b, onef.b, lacc[g], 0, 0, 0);
                lacc[g] = __builtin_amdgcn_mfma_f32_16x16x32_bf16(pf[g][1].b, onef.b, lacc[g], 0, 0, 0);
            }
            #pragma unroll
            for (int et = 0; et < 4; ++et) {
                FragU vf0, vf1;
                vf0.u = *(const ushort8*)&bV[(et*16+ln)*64 + ((2*quad    ) ^ p7) * 8];
                vf1.u = *(const ushort8*)&bV[(et*16+ln)*64 + ((2*quad + 1) ^ p7) * 8];
                #pragma unroll
                for (int g = 0; g < 2; ++g) {
                    o[g][et] = __builtin_amdgcn_mfma_f32_16x16x32_bf16(pf[g][0].b, vf0.b, o[g][et], 0, 0, 0);
                    o[g][et] = __builtin_amdgcn_mfma_f32_16x16x32_bf16(pf[g][1].b, vf1.b, o[g][et], 0, 0, 0);
                }
            }
            __builtin_amdgcn_s_setprio(0);
        }
        ++cur; if (cur == 3) cur = 0;
    }

    // Epilogue: lacc[g][r] holds l for row quad*4+r of group g on THIS lane
    // (C-layout row = quad*4 + reg, every col identical) -- no shuffles.
    #pragma unroll
    for (int g = 0; g < 2; ++g) {
        #pragma unroll
        for (int r = 0; r < 4; ++r) {
            const float invr = 1.f / lacc[g][r];
            float* op = Out + (((size_t)b * L_ + (qw + g * 16 + quad * 4 + r)) * H_ + h) * E_;
            #pragma unroll
            for (int et = 0; et < 4; ++et)
                op[et * 16 + ln] = o[g][et][r] * invr;
        }
    }
}

extern "C" void kernel_launch(void* const* d_in, const int* in_sizes, int n_in,
                              void* d_out, int out_size, void* d_ws, size_t ws_size,
                              hipStream_t stream) {
    const float* Q = (const float*)d_in[0];
    const float* K = (const float*)d_in[1];
    const float* V = (const float*)d_in[2];
    // d_in[3] (causal mask) applied analytically in-kernel.
    float* Out = (float*)d_out;

    const size_t plane = (size_t)B_ * H_ * S_ * E_;
    unsigned short* Kbf = (unsigned short*)d_ws;
    unsigned short* Vt  = Kbf + plane;

    dim3 grid(H_, L_ / 128, B_);         // x = head: pins (b,h) to one XCD
    if (ws_size >= plane * 2 * sizeof(unsigned short)) {
        conv_k<<<(int)(plane / 8 / 256), 256, 0, stream>>>(K, Kbf);
        conv_v<<<B_ * H_ * (S_ / 64), 256, 0, stream>>>(V, Vt);
        fattn_kernel<true><<<grid, dim3(256), 0, stream>>>(Q, Kbf, Vt, K, V, Out);
    } else {
        fattn_kernel<false><<<grid, dim3(256), 0, stream>>>(Q, Kbf, Vt, K, V, Out);
    }
}

// Round 5
// 228.421 us; speedup vs baseline: 1.1344x; 1.1344x over previous
//
#include <hip/hip_runtime.h>
#include <cmath>
#include <type_traits>

#define B_ 4
#define L_ 2048
#define S_ 2048
#define H_ 16
#define E_ 64
// 1/sqrt(64) * log2(e): exp2 (single v_exp_f32) instead of exp
#define SCALE2 0.18033688011112042f

typedef __attribute__((ext_vector_type(4))) float f32x4;
typedef __attribute__((ext_vector_type(8))) __bf16 bf16x8;
typedef __attribute__((ext_vector_type(8))) unsigned short ushort8;
union FragU { ushort8 u; bf16x8 b; unsigned int d[4]; };

__device__ __forceinline__ unsigned short f2bf(float f) {
    unsigned int u = __float_as_uint(f);
    return (unsigned short)((u + 0x7FFFu + ((u >> 16) & 1u)) >> 16);
}

// pack two fp32 (truncate) into one dword of 2 bf16: {hi[31:16], lo[31:16]}
__device__ __forceinline__ unsigned int pack_bf(float hi, float lo) {
    return __builtin_amdgcn_perm(__float_as_uint(hi), __float_as_uint(lo),
                                 0x07060302u);
}

__device__ __forceinline__ void gload_lds16(const void* g, void* l) {
    __builtin_amdgcn_global_load_lds(
        (const __attribute__((address_space(1))) void*)g,
        (__attribute__((address_space(3))) void*)l, 16, 0, 0);
}

// ---- Prepass: K [b,s,h,e] fp32 -> Kbf [b,h,s,e] bf16, 16B chunks XOR-swizzled
// within each key row (dst chunk j holds src chunk j^(s&7)).
__global__ __launch_bounds__(256) void conv_k(const float* __restrict__ K,
                                              unsigned short* __restrict__ Kbf) {
    const int idx = blockIdx.x * 256 + threadIdx.x;
    const int j   = idx & 7;
    const int row = idx >> 3;            // (b*H+h)*S + s
    const int s   = row & (S_ - 1);
    const int bh  = row >> 11;
    const int h   = bh & (H_ - 1);
    const int b   = bh >> 4;
    const int jp  = j ^ (s & 7);
    const float* src = K + (((size_t)b * S_ + s) * H_ + h) * E_ + jp * 8;
    f32x4 a = *(const f32x4*)src;
    f32x4 d = *(const f32x4*)(src + 4);
    ushort8 u;
    u[0]=f2bf(a[0]); u[1]=f2bf(a[1]); u[2]=f2bf(a[2]); u[3]=f2bf(a[3]);
    u[4]=f2bf(d[0]); u[5]=f2bf(d[1]); u[6]=f2bf(d[2]); u[7]=f2bf(d[3]);
    *(ushort8*)(Kbf + (size_t)row * E_ + j * 8) = u;
}

// ---- Prepass: V [b,s,h,e] fp32 -> Vt [b,h,e,s'] bf16, transposed per head,
// with the PERMUTED-K interleave baked in: within each 64-key block, stored
// chunk cc (= q*2+half) holds keys {(2*half+d)*16 + q*4 + r : d=0,1; r=0..3},
// then chunks XOR-swizzled by (e&7). This makes the main kernel's V B-frags
// (k = quad*8+j <-> key = (j>=4?n_hi:n_lo)*16+quad*4+(j&3)) plain b128 reads.
__global__ __launch_bounds__(256) void conv_v(const float* __restrict__ V,
                                              unsigned short* __restrict__ Vt) {
    __shared__ unsigned short t[64 * 65];
    const int tid  = threadIdx.x;
    const int sblk = blockIdx.x & 31;
    const int h    = (blockIdx.x >> 5) & 15;
    const int b    = blockIdx.x >> 9;
    const int s0   = sblk * 64;
    for (int i = 0; i < 4; ++i) {
        const int c = tid + i * 256;
        const int sr = c >> 4, e0 = (c & 15) * 4;
        f32x4 a = *(const f32x4*)(V + (((size_t)b * S_ + s0 + sr) * H_ + h) * E_ + e0);
        t[sr * 65 + e0 + 0] = f2bf(a[0]);
        t[sr * 65 + e0 + 1] = f2bf(a[1]);
        t[sr * 65 + e0 + 2] = f2bf(a[2]);
        t[sr * 65 + e0 + 3] = f2bf(a[3]);
    }
    __syncthreads();
    for (int i = 0; i < 2; ++i) {
        const int c  = tid + i * 256;
        const int e  = c >> 3, cc = c & 7;
        const int q  = cc >> 1, half = cc & 1;
        ushort8 u;
        for (int j = 0; j < 8; ++j) {
            const int d = j >> 2, r = j & 3;
            const int key = (2 * half + d) * 16 + q * 4 + r;
            u[j] = t[key * 65 + e];
        }
        *(ushort8*)(Vt + ((size_t)(b * H_ + h) * E_ + e) * S_ + s0
                    + (cc ^ (e & 7)) * 8) = u;
    }
}

// ---- Main: 4 waves x 32 q-rows = 128 q-rows/block, two 16-row groups per
// wave sharing every K/V LDS fragment. R4 = the proven recombination:
//   - R2 skeleton: 2 LDS buffers (32KB), __syncthreads, depth-1 prefetch
//     -> 4 blocks/CU (R3's 3rd buffer cost a block of occupancy, net loss).
//   - R3's XCD pin: h = blockIdx.x so all q-tiles of a (b,h) share id%8
//     (same XCD L2); staging is L2-fed (FETCH collapsed 119->33MB), so
//     depth-1's exposed latency is small.
//   - R3's l = P.1 via MFMA into lacc (idle matrix pipe, shuffle-free
//     epilogue).
//   - Diag-specialized softmax -- the cmp/cndmask mask chain exists
//     only in the ONE diagonal tile per wave, not the ~94% unmasked tiles.
template <bool PRE>
__global__ __launch_bounds__(256, 4) void fattn_kernel(
    const float* __restrict__ Q, const unsigned short* __restrict__ Kbf,
    const unsigned short* __restrict__ Vt, const float* __restrict__ Kf,
    const float* __restrict__ Vf, float* __restrict__ Out)
{
    const int tid  = threadIdx.x;
    const int wave = tid >> 6;
    const int lane = tid & 63;
    const int ln   = lane & 15;
    const int quad = lane >> 4;
    const int h = blockIdx.x;            // id%8 == h%8 -> per-(b,h) XCD pin
    const int b = blockIdx.z;
    // qtile bijective in y per (h,b); co-resident blocks (ids +256k) differ
    // in z -> qtile spread by 4 -> per-CU work within ~18% of mean.
    const int qtile = (blockIdx.y + blockIdx.x + 4 * blockIdx.z) & 15;
    const int q0 = qtile * 128;
    const int qw = q0 + wave * 32;       // this wave's 32 q-rows
    const int p7 = ln & 7;

    __shared__ __align__(16) unsigned short ldsK[2][64 * 64];  // [key][e] swz
    __shared__ __align__(16) unsigned short ldsV[2][64 * 64];  // [e][key'] swz

    // Q fragments (B-operand for S^T; n=ln, k=c*32+quad*8+j), pre-scaled.
    FragU qf[2][2];
    #pragma unroll
    for (int g = 0; g < 2; ++g) {
        const float* qp = Q + (((size_t)b * L_ + (qw + g * 16 + ln)) * H_ + h) * E_;
        #pragma unroll
        for (int c = 0; c < 2; ++c) {
            const int e0 = c * 32 + quad * 8;
            f32x4 lo = *(const f32x4*)(qp + e0);
            f32x4 hi = *(const f32x4*)(qp + e0 + 4);
            ushort8 u;
            u[0]=f2bf(lo[0]*SCALE2); u[1]=f2bf(lo[1]*SCALE2);
            u[2]=f2bf(lo[2]*SCALE2); u[3]=f2bf(lo[3]*SCALE2);
            u[4]=f2bf(hi[0]*SCALE2); u[5]=f2bf(hi[1]*SCALE2);
            u[6]=f2bf(hi[2]*SCALE2); u[7]=f2bf(hi[3]*SCALE2);
            qf[g][c].u = u;
        }
    }

    FragU onef;                          // all-ones bf16 B-frag for l = P.1
    #pragma unroll
    for (int j = 0; j < 8; ++j) onef.u[j] = 0x3F80;

    f32x4 o[2][4];
    #pragma unroll
    for (int g = 0; g < 2; ++g)
        #pragma unroll
        for (int et = 0; et < 4; ++et) o[g][et] = f32x4{0.f, 0.f, 0.f, 0.f};
    f32x4 lacc[2];
    lacc[0] = f32x4{0.f, 0.f, 0.f, 0.f};
    lacc[1] = f32x4{0.f, 0.f, 0.f, 0.f};

    const unsigned short* kbh = Kbf + (size_t)(b * H_ + h) * S_ * E_;
    const unsigned short* vbh = Vt  + (size_t)(b * H_ + h) * E_ * S_;
    const float* kf32 = Kf + (((size_t)b * S_) * H_ + h) * E_;
    const float* vf32 = Vf + (((size_t)b * S_) * H_ + h) * E_;

    auto STAGE = [&](int bsel, int kt2) {
        const int k0s = kt2 * 64;
        if constexpr (PRE) {
            const unsigned short* ktb = kbh + (size_t)k0s * E_;
            const unsigned short* vtb = vbh + k0s;
            #pragma unroll
            for (int i = 0; i < 2; ++i) {          // K tile: 8KB linear DMA
                const int slot0 = wave * 128 + i * 64;
                gload_lds16(ktb + (size_t)(slot0 + lane) * 8,
                            &ldsK[bsel][slot0 * 8]);
            }
            #pragma unroll
            for (int i = 0; i < 2; ++i) {          // V tile: 64 rows x 128B DMA
                const int slot0 = wave * 128 + i * 64;
                const int slot  = slot0 + lane;
                const int e = slot >> 3, lc = slot & 7;
                gload_lds16(vtb + (size_t)e * S_ + lc * 8,
                            &ldsV[bsel][slot0 * 8]);
            }
        } else {
            #pragma unroll
            for (int i = 0; i < 2; ++i) {          // fp32 fallback staging
                const int c = tid + i * 256;
                const int key = c >> 3, j = c & 7, jp = j ^ (key & 7);
                const float* src = kf32 + (size_t)(k0s + key) * (H_ * E_) + jp * 8;
                f32x4 a = *(const f32x4*)src, d = *(const f32x4*)(src + 4);
                ushort8 u;
                u[0]=f2bf(a[0]); u[1]=f2bf(a[1]); u[2]=f2bf(a[2]); u[3]=f2bf(a[3]);
                u[4]=f2bf(d[0]); u[5]=f2bf(d[1]); u[6]=f2bf(d[2]); u[7]=f2bf(d[3]);
                *(ushort8*)&ldsK[bsel][key * 64 + j * 8] = u;
            }
            #pragma unroll
            for (int i = 0; i < 2; ++i) {          // V with permuted-k layout
                const int c = tid + i * 256;
                const int e = c >> 3, cc = c & 7;
                const int q = cc >> 1, half = cc & 1;
                ushort8 u;
                #pragma unroll
                for (int j = 0; j < 8; ++j) {
                    const int d = j >> 2, r = j & 3;
                    const int key = (2 * half + d) * 16 + q * 4 + r;
                    u[j] = f2bf(vf32[(size_t)(k0s + key) * (H_ * E_) + e]);
                }
                *(ushort8*)&ldsV[bsel][e * 64 + (cc ^ (e & 7)) * 8] = u;
            }
        }
    };

    const int ntiles = 2 * qtile + 2;    // keys 0 .. q0+127
    STAGE(0, 0);
    int cur = 0;
    for (int kt = 0; kt < ntiles; ++kt) {
        const int k0 = kt * 64;
        // Drains own vmcnt (tile kt resident) AND guarantees every wave
        // finished reading buf cur^1 (tile kt-1) before we overwrite it.
        __syncthreads();
        if (kt + 1 < ntiles) STAGE(cur ^ 1, kt + 1);

        if (k0 <= qw + 31) {             // wave-uniform skip of masked tiles
            __builtin_amdgcn_s_setprio(1);
            const unsigned short* bK = ldsK[cur];
            const unsigned short* bV = ldsV[cur];
            FragU pf[2][2];

            // S^T = K.Q^T : A = K-frag (m=key), B = Q-frag (n=qrow).
            // Each kf pair feeds BOTH q-groups. P packed straight into pf.
            // Specialized on the diagonal: exactly ONE tile per wave has
            // k0+63 > qw, and in that tile BOTH groups need masking (proof:
            // k0 is a multiple of 64, qw of 32, so the diag tile has
            // k0 >= qw-32, hence k0+63 >= qw+31 > qw+16).
            auto qk_phase = [&](auto masked) {
                #pragma unroll
                for (int n = 0; n < 4; ++n) {
                    FragU kf0, kf1;
                    kf0.u = *(const ushort8*)&bK[(n*16+ln)*64 + ((quad    ) ^ p7) * 8];
                    kf1.u = *(const ushort8*)&bK[(n*16+ln)*64 + ((4 + quad) ^ p7) * 8];
                    #pragma unroll
                    for (int g = 0; g < 2; ++g) {
                        f32x4 acc = f32x4{0.f, 0.f, 0.f, 0.f};
                        acc = __builtin_amdgcn_mfma_f32_16x16x32_bf16(kf0.b, qf[g][0].b, acc, 0, 0, 0);
                        acc = __builtin_amdgcn_mfma_f32_16x16x32_bf16(kf1.b, qf[g][1].b, acc, 0, 0, 0);
                        float p[4];
                        #pragma unroll
                        for (int r = 0; r < 4; ++r) {
                            float v = __builtin_exp2f(acc[r]);
                            if constexpr (decltype(masked)::value) {
                                const int key  = k0 + n * 16 + quad * 4 + r;
                                const int qrow = qw + g * 16 + ln;
                                v = (key <= qrow) ? v : 0.f;
                            }
                            p[r] = v;
                        }
                        pf[g][n >> 1].d[(n & 1) * 2 + 0] = pack_bf(p[1], p[0]);
                        pf[g][n >> 1].d[(n & 1) * 2 + 1] = pack_bf(p[3], p[2]);
                    }
                }
            };
            if (k0 + 63 > qw) qk_phase(std::integral_constant<bool, true>{});
            else              qk_phase(std::integral_constant<bool, false>{});

            // l += P.1 on the (mostly idle) MFMA pipe; O += P.V.
            #pragma unroll
            for (int g = 0; g < 2; ++g) {
                lacc[g] = __builtin_amdgcn_mfma_f32_16x16x32_bf16(pf[g][0].b, onef.b, lacc[g], 0, 0, 0);
                lacc[g] = __builtin_amdgcn_mfma_f32_16x16x32_bf16(pf[g][1].b, onef.b, lacc[g], 0, 0, 0);
            }
            #pragma unroll
            for (int et = 0; et < 4; ++et) {
                FragU vf0, vf1;
                vf0.u = *(const ushort8*)&bV[(et*16+ln)*64 + ((2*quad    ) ^ p7) * 8];
                vf1.u = *(const ushort8*)&bV[(et*16+ln)*64 + ((2*quad + 1) ^ p7) * 8];
                #pragma unroll
                for (int g = 0; g < 2; ++g) {
                    o[g][et] = __builtin_amdgcn_mfma_f32_16x16x32_bf16(pf[g][0].b, vf0.b, o[g][et], 0, 0, 0);
                    o[g][et] = __builtin_amdgcn_mfma_f32_16x16x32_bf16(pf[g][1].b, vf1.b, o[g][et], 0, 0, 0);
                }
            }
            __builtin_amdgcn_s_setprio(0);
        }
        cur ^= 1;
    }

    // Epilogue: lacc[g][r] holds l for row quad*4+r of group g on THIS lane
    // (C-layout row = quad*4 + reg, every col identical) -- no shuffles.
    #pragma unroll
    for (int g = 0; g < 2; ++g) {
        #pragma unroll
        for (int r = 0; r < 4; ++r) {
            const float invr = 1.f / lacc[g][r];
            float* op = Out + (((size_t)b * L_ + (qw + g * 16 + quad * 4 + r)) * H_ + h) * E_;
            #pragma unroll
            for (int et = 0; et < 4; ++et)
                op[et * 16 + ln] = o[g][et][r] * invr;
        }
    }
}

extern "C" void kernel_launch(void* const* d_in, const int* in_sizes, int n_in,
                              void* d_out, int out_size, void* d_ws, size_t ws_size,
                              hipStream_t stream) {
    const float* Q = (const float*)d_in[0];
    const float* K = (const float*)d_in[1];
    const float* V = (const float*)d_in[2];
    // d_in[3] (causal mask) applied analytically in-kernel.
    float* Out = (float*)d_out;

    const size_t plane = (size_t)B_ * H_ * S_ * E_;
    unsigned short* Kbf = (unsigned short*)d_ws;
    unsigned short* Vt  = Kbf + plane;

    dim3 grid(H_, L_ / 128, B_);         // x = head: pins (b,h) to one XCD
    if (ws_size >= plane * 2 * sizeof(unsigned short)) {
        conv_k<<<(int)(plane / 8 / 256), 256, 0, stream>>>(K, Kbf);
        conv_v<<<B_ * H_ * (S_ / 64), 256, 0, stream>>>(V, Vt);
        fattn_kernel<true><<<grid, dim3(256), 0, stream>>>(Q, Kbf, Vt, K, V, Out);
    } else {
        fattn_kernel<false><<<grid, dim3(256), 0, stream>>>(Q, Kbf, Vt, K, V, Out);
    }
}